// Round 5
// baseline (5678.791 us; speedup 1.0000x reference)
//
#include <hip/hip_runtime.h>
#include <hip/hip_bf16.h>

// DGMNet: B=65536, IN=16, H=1024, L=4, OUT=1. All I/O fp32, bf16 MFMA inside.
// Round-5: (a) non-temporal stream accesses so the 2 MiB weight tables stay
// L2-resident (round-4 PMC showed ~600 MB/dispatch of table re-fetch = ~0% L2
// hit); (b) fuse Z-pass into the layer kernel (ZS held in registers, bf16
// packed) and G-pass into the head kernel; (c) stream footprint 4 KiB/row ->
// chunk 15232 rows -> grid 238/256 CUs, 25 launches total.

typedef float f32x4 __attribute__((ext_vector_type(4)));
typedef __bf16 bf16x8 __attribute__((ext_vector_type(8)));
typedef unsigned int u32x4 __attribute__((ext_vector_type(4)));

#define MFMA16 __builtin_amdgcn_mfma_f32_16x16x32_bf16

// ---------- ws layout ----------
#define WS_WZ   0u
#define WS_WG   (2u << 20)
#define WS_XT   (4u << 20)
#define WS_BIAS ((4u << 20) + 6u * 65536u)
#define WS_S2   ((size_t)4718592)          // streams start at 4.5 MiB
#define WS_S    ((size_t)8 << 20)          // fallback-era constant (unused by split)

static __device__ __forceinline__ unsigned short f2bf(float f) {
    __hip_bfloat16 h = __float2bfloat16(f);
    union { __hip_bfloat16 h; unsigned short u; } c; c.h = h; return c.u;
}
static __device__ __forceinline__ float bf2f(unsigned short u) {
    union { unsigned int u; float f; } c; c.u = ((unsigned int)u) << 16; return c.f;
}
static __device__ __forceinline__ float fast_tanh(float x) {
    float e = __expf(2.0f * x);
    return 1.0f - 2.0f * __builtin_amdgcn_rcpf(e + 1.0f);
}
// LDS swizzle for [rows][1024] bf16 tiles (G4 bank-conflict fix)
static __device__ __forceinline__ unsigned int swoff(int row, int kelem) {
    unsigned int a = (unsigned int)(row * 2048 + kelem * 2);
    return a ^ (unsigned int)((row & 7) << 4);
}
// non-temporal 16B helpers (bypass L2 allocation for stream traffic)
static __device__ __forceinline__ u32x4 ntl4(const void* p) {
    return __builtin_nontemporal_load((const u32x4*)p);
}
static __device__ __forceinline__ void nts4(void* p, u32x4 v) {
    __builtin_nontemporal_store(v, (u32x4*)p);
}

// ---------------- prep kernels ----------------
__global__ void prep_big(const float* __restrict__ Wz, const float* __restrict__ Wg,
                         char* __restrict__ ws) {
    int bid = blockIdx.x;                 // 4096 blocks: mat(2) x ks(32) x cf(64)
    int mat = bid >> 11, rem = bid & 2047;
    int ks = rem >> 6, cf = rem & 63;
    const float* src = mat ? Wg : Wz;
    char* dst = ws + ((size_t)mat << 21) + ((size_t)(ks * 64 + cf) << 10);
    int l = threadIdx.x;
    int col = cf * 16 + (l & 15);
    int kb  = ks * 32 + ((l >> 4) << 3);
    unsigned short* d = (unsigned short*)(dst + l * 16);
    #pragma unroll
    for (int j = 0; j < 8; ++j) d[j] = f2bf(src[col * 1024 + kb + j]);
}

__global__ void prep_x(const float* __restrict__ Uz, const float* __restrict__ Ur,
                       const float* __restrict__ Uh, const float* __restrict__ Ug,
                       const float* __restrict__ Sw, char* __restrict__ xt) {
    int bid = blockIdx.x;                 // 384 blocks: gate(6) x cf(64)
    int g_ = bid >> 6, cf = bid & 63;
    int l = threadIdx.x;
    int col = cf * 16 + (l & 15);
    int kb  = (l >> 4) << 3;
    unsigned short* d = (unsigned short*)(xt + ((size_t)(g_ * 64 + cf) << 10) + l * 16);
    #pragma unroll
    for (int j = 0; j < 8; ++j) {
        int k = kb + j;
        float v = 0.0f;
        if (k < 16) {
            int idx = col * 16 + k;
            switch (g_) {
                case 0: v = Uz[idx]; break;
                case 1: v = Ur[idx]; break;
                case 2: v = Uh[idx]; break;
                case 3: v = Ug[idx]; break;
                case 4: v = Ur[idx] - Ug[idx]; break;
                case 5: v = Sw[idx]; break;
            }
        }
        d[j] = f2bf(v);
    }
}

__global__ void prep_bias(const float* __restrict__ Uz_b, const float* __restrict__ Wz_b,
                          const float* __restrict__ Ur_b, const float* __restrict__ Uh_b,
                          const float* __restrict__ Ug_b, const float* __restrict__ Wg_b,
                          const float* __restrict__ Sw_b, float* __restrict__ dst) {
    int i = blockIdx.x * 256 + threadIdx.x;
    dst[i]        = Uz_b[i] + Wz_b[i];        // bz
    dst[1024 + i] = Ur_b[i] + Wg_b[i];        // br
    dst[2048 + i] = Uh_b[i] + Wg_b[i];        // bh
    dst[3072 + i] = Ug_b[i] + Wg_b[i];        // bg
    dst[4096 + i] = Sw_b[i];                  // bs
}

// ================= SPLIT PATH: 1024-thread WGs, M=64, 16 waves =================

static __device__ __forceinline__ void stage_xb(const float* __restrict__ x,
                                                unsigned short* xb, int t, int tid) {
    for (int i = tid; i < 64 * 32; i += 1024) {
        int r = i >> 5, c = i & 31;
        float v = (c < 16) ? x[(size_t)(t * 64 + r) * 16 + c] : 0.0f;
        xb[i] = f2bf(v);
    }
}
static __device__ __forceinline__ void stage_S(const char* __restrict__ Sg,
                                               char* sbuf, int t, int tid) {
    for (int i = tid; i < 8192; i += 1024) {
        int r = i >> 7, c8 = i & 127;
        u32x4 v = ntl4(Sg + (size_t)(t * 64 + r) * 2048 + c8 * 16);
        *(u32x4*)(sbuf + swoff(r, c8 * 8)) = v;
    }
}
static __device__ __forceinline__ void unstage_S(const char* sbuf,
                                                 char* __restrict__ Sg, int t, int tid) {
    for (int i = tid; i < 8192; i += 1024) {
        int r = i >> 7, c8 = i & 127;
        u32x4 v = *(const u32x4*)(sbuf + swoff(r, c8 * 8));
        nts4(Sg + (size_t)(t * 64 + r) * 2048 + c8 * 16, v);
    }
}

// 16-wave fragment GEMMs: wave wv owns cols [wv*64, wv*64+64), 4 cf x 4 rf.
static __device__ __forceinline__ void mmx16(f32x4 (&acc)[4][4], const char* __restrict__ xtab,
                                             const unsigned short* xb, int lane, int wv) {
    const int c15 = lane & 15, h = lane >> 4;
    bf16x8 a[4];
    #pragma unroll
    for (int rf = 0; rf < 4; ++rf)
        a[rf] = *(const bf16x8*)(xb + (c15 + 16 * rf) * 32 + h * 8);
    #pragma unroll
    for (int cf = 0; cf < 4; ++cf) {
        bf16x8 b = *(const bf16x8*)(xtab + ((wv * 4 + cf) << 10) + lane * 16);
        #pragma unroll
        for (int rf = 0; rf < 4; ++rf) acc[rf][cf] = MFMA16(a[rf], b, acc[rf][cf], 0, 0, 0);
    }
}

static __device__ __forceinline__ void mms16(f32x4 (&acc)[4][4], const char* __restrict__ stab,
                                             const char* sb, int lane, int wv) {
    const int c15 = lane & 15, h = lane >> 4;
    #pragma unroll 2
    for (int ks = 0; ks < 32; ++ks) {
        const char* bp = stab + ((size_t)(ks * 64 + wv * 4) << 10) + lane * 16;
        bf16x8 b[4];
        #pragma unroll
        for (int cf = 0; cf < 4; ++cf) b[cf] = *(const bf16x8*)(bp + (cf << 10));
        bf16x8 a[4];
        #pragma unroll
        for (int rf = 0; rf < 4; ++rf)
            a[rf] = *(const bf16x8*)(sb + swoff(c15 + 16 * rf, (ks << 5) + (h << 3)));
        #pragma unroll
        for (int cf = 0; cf < 4; ++cf)
            #pragma unroll
            for (int rf = 0; rf < 4; ++rf)
                acc[rf][cf] = MFMA16(a[rf], b[cf], acc[rf][cf], 0, 0, 0);
    }
}

#define ZERO_ACC(acc) { _Pragma("unroll") for (int rf_ = 0; rf_ < 4; ++rf_) \
    _Pragma("unroll") for (int cf_ = 0; cf_ < 4; ++cf_) acc[rf_][cf_] = (f32x4)0.0f; }

// head: S1 = x @ Sw^T + bs (raw) -> Sg; G = tanh(ux_g + S1@Wg^T + bg) -> packed Gp
__global__ __launch_bounds__(1024, 4)
void k_head(const float* __restrict__ x, const char* __restrict__ ws,
            char* __restrict__ Sg, char* __restrict__ Gp) {
    extern __shared__ char lds[];
    char* sbuf = lds;
    unsigned short* xb = (unsigned short*)(lds + 131072);
    const int tid = threadIdx.x, lane = tid & 63, wv = tid >> 6, t = blockIdx.x;
    const int c15 = lane & 15, h = lane >> 4;
    stage_xb(x, xb, t, tid);
    __syncthreads();
    f32x4 acc[4][4];
    // ---- S1 ----
    ZERO_ACC(acc);
    mmx16(acc, ws + WS_XT + 5 * 65536, xb, lane, wv);
    const float* BS = (const float*)(ws + WS_BIAS) + 4096;
    #pragma unroll
    for (int cf = 0; cf < 4; ++cf) {
        int col = (wv << 6) + (cf << 4) + c15;
        float b = BS[col];
        #pragma unroll
        for (int rf = 0; rf < 4; ++rf)
            #pragma unroll
            for (int r = 0; r < 4; ++r) {
                int row = (rf << 4) + (h << 2) + r;
                *(unsigned short*)(sbuf + swoff(row, col)) = f2bf(acc[rf][cf][r] + b);
            }
    }
    __syncthreads();
    unstage_S(sbuf, Sg, t, tid);
    // ---- G ----
    ZERO_ACC(acc);
    mmx16(acc, ws + WS_XT + 3 * 65536, xb, lane, wv);
    mms16(acc, ws + WS_WG, sbuf, lane, wv);
    const float* BG = (const float*)(ws + WS_BIAS) + 3072;
    unsigned int pk[32];
    #pragma unroll
    for (int cf = 0; cf < 4; ++cf) {
        int col = (wv << 6) + (cf << 4) + c15;
        float b = BG[col];
        #pragma unroll
        for (int rf = 0; rf < 4; ++rf) {
            float v[4];
            #pragma unroll
            for (int r = 0; r < 4; ++r) v[r] = fast_tanh(acc[rf][cf][r] + b);
            pk[(rf * 4 + cf) * 2 + 0] = (unsigned int)f2bf(v[0]) | ((unsigned int)f2bf(v[1]) << 16);
            pk[(rf * 4 + cf) * 2 + 1] = (unsigned int)f2bf(v[2]) | ((unsigned int)f2bf(v[3]) << 16);
        }
    }
    char* dt = Gp + ((size_t)t << 17);
    #pragma unroll
    for (int w = 0; w < 8; ++w) {
        u32x4 q = { pk[w * 4], pk[w * 4 + 1], pk[w * 4 + 2], pk[w * 4 + 3] };
        nts4(dt + w * 16384 + tid * 16, q);
    }
}

// layer: Z (Wz) -> regs; R (Wg) -> SR in LDS; H (Wg); o=(1-G)H+ZS;
// last==0: S <- tanh(o) -> Sg; last==1: out = o . ow + ob
__global__ __launch_bounds__(1024, 4)
void k_lyr(const float* __restrict__ x, const char* __restrict__ ws,
           char* __restrict__ Sg, const char* __restrict__ Gp, int last,
           const float* __restrict__ ow, const float* __restrict__ ob,
           float* __restrict__ outp) {
    extern __shared__ char lds[];
    char* sbuf = lds;
    unsigned short* xb = (unsigned short*)(lds + 131072);
    float* red = (float*)(lds + 131072 + 4096);
    const int tid = threadIdx.x, lane = tid & 63, wv = tid >> 6, t = blockIdx.x;
    const int c15 = lane & 15, h = lane >> 4;
    stage_S(Sg, sbuf, t, tid);
    stage_xb(x, xb, t, tid);
    __syncthreads();

    const float* BZ = (const float*)(ws + WS_BIAS);
    const float* BR = BZ + 1024;
    const float* BH = BZ + 2048;

    f32x4 acc[4][4];
    // ---- Z pass (Wz): ZS -> packed regs ----
    ZERO_ACC(acc);
    mmx16(acc, ws + WS_XT + 0 * 65536, xb, lane, wv);
    mms16(acc, ws + WS_WZ, sbuf, lane, wv);
    unsigned int zsp[32];
    #pragma unroll
    for (int cf = 0; cf < 4; ++cf) {
        int col = (wv << 6) + (cf << 4) + c15;
        float bzl = BZ[col];
        #pragma unroll
        for (int rf = 0; rf < 4; ++rf) {
            float v[4];
            #pragma unroll
            for (int r = 0; r < 4; ++r) {
                int row = (rf << 4) + (h << 2) + r;
                float z = fast_tanh(acc[rf][cf][r] + bzl);
                v[r] = z * bf2f(*(const unsigned short*)(sbuf + swoff(row, col)));
            }
            zsp[(rf * 4 + cf) * 2 + 0] = (unsigned int)f2bf(v[0]) | ((unsigned int)f2bf(v[1]) << 16);
            zsp[(rf * 4 + cf) * 2 + 1] = (unsigned int)f2bf(v[2]) | ((unsigned int)f2bf(v[3]) << 16);
        }
    }

    // ---- R pass (Wg): SR -> packed regs ----
    ZERO_ACC(acc);
    mmx16(acc, ws + WS_XT + 1 * 65536, xb, lane, wv);
    mms16(acc, ws + WS_WG, sbuf, lane, wv);
    unsigned int srp[32];
    #pragma unroll
    for (int cf = 0; cf < 4; ++cf) {
        int col = (wv << 6) + (cf << 4) + c15;
        float brl = BR[col];
        #pragma unroll
        for (int rf = 0; rf < 4; ++rf) {
            float v[4];
            #pragma unroll
            for (int r = 0; r < 4; ++r) {
                int row = (rf << 4) + (h << 2) + r;
                float rv = fast_tanh(acc[rf][cf][r] + brl);
                v[r] = rv * bf2f(*(const unsigned short*)(sbuf + swoff(row, col)));
            }
            srp[(rf * 4 + cf) * 2 + 0] = (unsigned int)f2bf(v[0]) | ((unsigned int)f2bf(v[1]) << 16);
            srp[(rf * 4 + cf) * 2 + 1] = (unsigned int)f2bf(v[2]) | ((unsigned int)f2bf(v[3]) << 16);
        }
    }
    __syncthreads();   // all S reads (incl. other waves' A-frags) done
    #pragma unroll
    for (int cf = 0; cf < 4; ++cf) {
        int col = (wv << 6) + (cf << 4) + c15;
        #pragma unroll
        for (int rf = 0; rf < 4; ++rf)
            #pragma unroll
            for (int r = 0; r < 4; ++r) {
                int row = (rf << 4) + (h << 2) + r;
                unsigned short u = (unsigned short)((srp[(rf * 4 + cf) * 2 + (r >> 1)] >> ((r & 1) * 16)) & 0xffff);
                *(unsigned short*)(sbuf + swoff(row, col)) = u;
            }
    }
    __syncthreads();   // SR ready

    // ---- H pass (Wg) ----
    ZERO_ACC(acc);
    mmx16(acc, ws + WS_XT + 2 * 65536, xb, lane, wv);
    mms16(acc, ws + WS_WG, sbuf, lane, wv);
    __syncthreads();   // all SR reads done before in-place newS writes

    const char* gt = Gp + ((size_t)t << 17);
    if (!last) {
        #pragma unroll
        for (int w = 0; w < 8; ++w) {
            u32x4 g4 = ntl4(gt + w * 16384 + tid * 16);
            #pragma unroll
            for (int jj = 0; jj < 2; ++jj) {
                int rfcf = w * 2 + jj;
                int rf = rfcf >> 2, cf = rfcf & 3;
                int col = (wv << 6) + (cf << 4) + c15;
                float bhl = BH[col];
                #pragma unroll
                for (int r = 0; r < 4; ++r) {
                    int row = (rf << 4) + (h << 2) + r;
                    float g  = bf2f((unsigned short)((g4[jj * 2 + (r >> 1)] >> ((r & 1) * 16)) & 0xffff));
                    float zs = bf2f((unsigned short)((zsp[rfcf * 2 + (r >> 1)] >> ((r & 1) * 16)) & 0xffff));
                    float hv = fast_tanh(acc[rf][cf][r] + bhl);
                    float o  = (1.0f - g) * hv + zs;
                    *(unsigned short*)(sbuf + swoff(row, col)) = f2bf(fast_tanh(o));
                }
            }
        }
        __syncthreads();
        unstage_S(sbuf, Sg, t, tid);
    } else {
        float po[16];
        #pragma unroll
        for (int i = 0; i < 16; ++i) po[i] = 0.0f;
        #pragma unroll
        for (int w = 0; w < 8; ++w) {
            u32x4 g4 = ntl4(gt + w * 16384 + tid * 16);
            #pragma unroll
            for (int jj = 0; jj < 2; ++jj) {
                int rfcf = w * 2 + jj;
                int rf = rfcf >> 2, cf = rfcf & 3;
                int col = (wv << 6) + (cf << 4) + c15;
                float bhl = BH[col];
                float oww = ow[col];
                #pragma unroll
                for (int r = 0; r < 4; ++r) {
                    float g  = bf2f((unsigned short)((g4[jj * 2 + (r >> 1)] >> ((r & 1) * 16)) & 0xffff));
                    float zs = bf2f((unsigned short)((zsp[rfcf * 2 + (r >> 1)] >> ((r & 1) * 16)) & 0xffff));
                    float hv = fast_tanh(acc[rf][cf][r] + bhl);
                    po[(rf << 2) + r] += ((1.0f - g) * hv + zs) * oww;
                }
            }
        }
        #pragma unroll
        for (int off = 1; off < 16; off <<= 1)
            #pragma unroll
            for (int i = 0; i < 16; ++i) po[i] += __shfl_xor(po[i], off);
        if (c15 == 0) {
            #pragma unroll
            for (int rf = 0; rf < 4; ++rf)
                #pragma unroll
                for (int r = 0; r < 4; ++r)
                    red[wv * 64 + (rf << 4) + (h << 2) + r] = po[(rf << 2) + r];
        }
        __syncthreads();
        if (tid < 64) {
            float s = ob[0];
            #pragma unroll
            for (int w = 0; w < 16; ++w) s += red[w * 64 + tid];
            outp[t * 64 + tid] = s;
        }
    }
}

// ================= FALLBACK PATH: round-1 fused kernel (proven) =================

static __device__ __forceinline__ void mm_x(f32x4 acc[2][8], const char* __restrict__ xtab,
                                            const unsigned short* __restrict__ xb,
                                            int lane, int wv) {
    const int c15 = lane & 15, h = lane >> 4;
    bf16x8 a0 = *(const bf16x8*)(xb + c15 * 48 + h * 8);
    bf16x8 a1 = *(const bf16x8*)(xb + (c15 + 16) * 48 + h * 8);
    #pragma unroll
    for (int cf = 0; cf < 8; ++cf) {
        bf16x8 b = *(const bf16x8*)(xtab + ((wv * 8 + cf) << 10) + lane * 16);
        acc[0][cf] = MFMA16(a0, b, acc[0][cf], 0, 0, 0);
        acc[1][cf] = MFMA16(a1, b, acc[1][cf], 0, 0, 0);
    }
}

static __device__ __forceinline__ void mm_s(f32x4 acc[2][8], const char* __restrict__ stab,
                                            const char* __restrict__ sb, int lane, int wv) {
    const int c15 = lane & 15, h = lane >> 4;
    #pragma unroll 2
    for (int ks = 0; ks < 32; ++ks) {
        const char* bp = stab + ((size_t)(ks * 64 + wv * 8) << 10) + lane * 16;
        bf16x8 b[8];
        #pragma unroll
        for (int cf = 0; cf < 8; ++cf) b[cf] = *(const bf16x8*)(bp + (cf << 10));
        bf16x8 a0 = *(const bf16x8*)(sb + swoff(c15,      (ks << 5) + (h << 3)));
        bf16x8 a1 = *(const bf16x8*)(sb + swoff(c15 + 16, (ks << 5) + (h << 3)));
        #pragma unroll
        for (int cf = 0; cf < 8; ++cf) {
            acc[0][cf] = MFMA16(a0, b[cf], acc[0][cf], 0, 0, 0);
            acc[1][cf] = MFMA16(a1, b[cf], acc[1][cf], 0, 0, 0);
        }
    }
}

__global__ __launch_bounds__(512, 2)
void dgm_main(const float* __restrict__ x, const float* __restrict__ out_w,
              const float* __restrict__ out_b, const char* __restrict__ ws,
              float* __restrict__ out) {
    extern __shared__ char lds[];
    char* sbuf0 = lds;
    char* sbuf1 = lds + 65536;
    unsigned short* xb = (unsigned short*)(lds + 131072);
    float* red = (float*)(lds + 131072 + 3072);

    const int tid = threadIdx.x, lane = tid & 63, wv = tid >> 6;
    const int c15 = lane & 15, h = lane >> 4;
    const int t = blockIdx.x;

    const char* WZ = ws + WS_WZ;
    const char* WG = ws + WS_WG;
    const char* XT = ws + WS_XT;
    const float* BZ = (const float*)(ws + WS_BIAS);
    const float* BR = BZ + 1024;
    const float* BH = BZ + 2048;
    const float* BG = BZ + 3072;
    const float* BS = BZ + 4096;

    for (int i = tid; i < 32 * 48; i += 512) {
        int r_ = i / 48, c_ = i % 48;
        float v = (c_ < 16) ? x[(t * 32 + r_) * 16 + c_] : 0.0f;
        xb[r_ * 48 + c_] = f2bf(v);
    }
    __syncthreads();

    f32x4 acc[2][8];
    unsigned int g1m[2][8][2];
    unsigned int zs[2][8][2];
    float po[8];
    #pragma unroll
    for (int i = 0; i < 8; ++i) po[i] = 0.0f;

    #pragma unroll
    for (int rf = 0; rf < 2; ++rf)
        #pragma unroll
        for (int cf = 0; cf < 8; ++cf) acc[rf][cf] = (f32x4)0.0f;
    mm_x(acc, XT + 5 * 65536, xb, lane, wv);
    #pragma unroll
    for (int cf = 0; cf < 8; ++cf) {
        int col = (wv << 7) + (cf << 4) + c15;
        float b = BS[col];
        #pragma unroll
        for (int rf = 0; rf < 2; ++rf)
            #pragma unroll
            for (int r = 0; r < 4; ++r) {
                int row = (rf << 4) + (h << 2) + r;
                *(unsigned short*)(sbuf0 + swoff(row, col)) = f2bf(acc[rf][cf][r] + b);
            }
    }
    __syncthreads();

    {
        #pragma unroll
        for (int rf = 0; rf < 2; ++rf)
            #pragma unroll
            for (int cf = 0; cf < 8; ++cf) acc[rf][cf] = (f32x4)0.0f;
        mm_x(acc, XT + 3 * 65536, xb, lane, wv);
        mm_s(acc, WG, sbuf0, lane, wv);
        unsigned int wgx[2][8][2];
        #pragma unroll
        for (int rf = 0; rf < 2; ++rf)
            #pragma unroll
            for (int cf = 0; cf < 8; ++cf) {
                wgx[rf][cf][0] = (unsigned int)f2bf(acc[rf][cf][0]) |
                                 ((unsigned int)f2bf(acc[rf][cf][1]) << 16);
                wgx[rf][cf][1] = (unsigned int)f2bf(acc[rf][cf][2]) |
                                 ((unsigned int)f2bf(acc[rf][cf][3]) << 16);
            }
        #pragma unroll
        for (int rf = 0; rf < 2; ++rf)
            #pragma unroll
            for (int cf = 0; cf < 8; ++cf) acc[rf][cf] = (f32x4)0.0f;
        mm_x(acc, XT + 4 * 65536, xb, lane, wv);
        #pragma unroll
        for (int cf = 0; cf < 8; ++cf) {
            int col = (wv << 7) + (cf << 4) + c15;
            float brl = BR[col], bgl = BG[col];
            #pragma unroll
            for (int rf = 0; rf < 2; ++rf) {
                float g1v[4];
                #pragma unroll
                for (int r = 0; r < 4; ++r) {
                    int row = (rf << 4) + (h << 2) + r;
                    float wgv = bf2f((unsigned short)((wgx[rf][cf][r >> 1] >> ((r & 1) * 16)) & 0xffff));
                    float rv = fast_tanh(wgv + acc[rf][cf][r] + brl);
                    float s1 = bf2f(*(const unsigned short*)(sbuf0 + swoff(row, col)));
                    *(unsigned short*)(sbuf1 + swoff(row, col)) = f2bf(s1 * rv);
                    g1v[r] = 1.0f - fast_tanh(wgv + bgl);
                }
                g1m[rf][cf][0] = (unsigned int)f2bf(g1v[0]) | ((unsigned int)f2bf(g1v[1]) << 16);
                g1m[rf][cf][1] = (unsigned int)f2bf(g1v[2]) | ((unsigned int)f2bf(g1v[3]) << 16);
            }
        }
    }
    __syncthreads();

    char* cur = sbuf0;
    char* oth = sbuf1;
    #pragma clang loop unroll(disable)
    for (int L = 0; L < 4; ++L) {
        #pragma unroll
        for (int rf = 0; rf < 2; ++rf)
            #pragma unroll
            for (int cf = 0; cf < 8; ++cf) acc[rf][cf] = (f32x4)0.0f;
        mm_x(acc, XT + 0 * 65536, xb, lane, wv);
        mm_s(acc, WZ, cur, lane, wv);
        #pragma unroll
        for (int cf = 0; cf < 8; ++cf) {
            int col = (wv << 7) + (cf << 4) + c15;
            float bzl = BZ[col];
            #pragma unroll
            for (int rf = 0; rf < 2; ++rf) {
                float zv[4];
                #pragma unroll
                for (int r = 0; r < 4; ++r) {
                    int row = (rf << 4) + (h << 2) + r;
                    float z = fast_tanh(acc[rf][cf][r] + bzl);
                    float s = bf2f(*(const unsigned short*)(cur + swoff(row, col)));
                    zv[r] = z * s;
                }
                zs[rf][cf][0] = (unsigned int)f2bf(zv[0]) | ((unsigned int)f2bf(zv[1]) << 16);
                zs[rf][cf][1] = (unsigned int)f2bf(zv[2]) | ((unsigned int)f2bf(zv[3]) << 16);
            }
        }
        if (L > 0) {
            #pragma unroll
            for (int rf = 0; rf < 2; ++rf)
                #pragma unroll
                for (int cf = 0; cf < 8; ++cf) acc[rf][cf] = (f32x4)0.0f;
            mm_x(acc, XT + 1 * 65536, xb, lane, wv);
            mm_s(acc, WG, cur, lane, wv);
            #pragma unroll
            for (int cf = 0; cf < 8; ++cf) {
                int col = (wv << 7) + (cf << 4) + c15;
                float brl = BR[col];
                #pragma unroll
                for (int rf = 0; rf < 2; ++rf)
                    #pragma unroll
                    for (int r = 0; r < 4; ++r) {
                        int row = (rf << 4) + (h << 2) + r;
                        float rv = fast_tanh(acc[rf][cf][r] + brl);
                        float s = bf2f(*(const unsigned short*)(cur + swoff(row, col)));
                        *(unsigned short*)(oth + swoff(row, col)) = f2bf(s * rv);
                    }
            }
        }
        __syncthreads();
        #pragma unroll
        for (int rf = 0; rf < 2; ++rf)
            #pragma unroll
            for (int cf = 0; cf < 8; ++cf) acc[rf][cf] = (f32x4)0.0f;
        mm_x(acc, XT + 2 * 65536, xb, lane, wv);
        mm_s(acc, WG, oth, lane, wv);
        __syncthreads();
        if (L < 3) {
            #pragma unroll
            for (int cf = 0; cf < 8; ++cf) {
                int col = (wv << 7) + (cf << 4) + c15;
                float bhl = BH[col];
                #pragma unroll
                for (int rf = 0; rf < 2; ++rf)
                    #pragma unroll
                    for (int r = 0; r < 4; ++r) {
                        int row = (rf << 4) + (h << 2) + r;
                        float hv = fast_tanh(acc[rf][cf][r] + bhl);
                        float g1 = bf2f((unsigned short)((g1m[rf][cf][r >> 1] >> ((r & 1) * 16)) & 0xffff));
                        float zsv = bf2f((unsigned short)((zs[rf][cf][r >> 1] >> ((r & 1) * 16)) & 0xffff));
                        float o = g1 * hv + zsv;
                        *(unsigned short*)(oth + swoff(row, col)) = f2bf(fast_tanh(o));
                    }
            }
        } else {
            #pragma unroll
            for (int cf = 0; cf < 8; ++cf) {
                int col = (wv << 7) + (cf << 4) + c15;
                float bhl = BH[col];
                float oww = out_w[col];
                #pragma unroll
                for (int rf = 0; rf < 2; ++rf)
                    #pragma unroll
                    for (int r = 0; r < 4; ++r) {
                        float hv = fast_tanh(acc[rf][cf][r] + bhl);
                        float g1 = bf2f((unsigned short)((g1m[rf][cf][r >> 1] >> ((r & 1) * 16)) & 0xffff));
                        float zsv = bf2f((unsigned short)((zs[rf][cf][r >> 1] >> ((r & 1) * 16)) & 0xffff));
                        po[(rf << 2) + r] += (g1 * hv + zsv) * oww;
                    }
            }
        }
        __syncthreads();
        char* tmp = cur; cur = oth; oth = tmp;
    }

    #pragma unroll
    for (int off = 1; off < 16; off <<= 1)
        #pragma unroll
        for (int i = 0; i < 8; ++i) po[i] += __shfl_xor(po[i], off);
    if (c15 == 0) {
        #pragma unroll
        for (int rf = 0; rf < 2; ++rf)
            #pragma unroll
            for (int r = 0; r < 4; ++r)
                red[wv * 32 + (rf << 4) + (h << 2) + r] = po[(rf << 2) + r];
    }
    __syncthreads();
    if (tid < 32) {
        float s = out_b[0];
        #pragma unroll
        for (int w = 0; w < 8; ++w) s += red[w * 32 + tid];
        out[t * 32 + tid] = s;
    }
}

// ---------------- host ----------------
extern "C" void kernel_launch(void* const* d_in, const int* in_sizes, int n_in,
                              void* d_out, int out_size, void* d_ws, size_t ws_size,
                              hipStream_t stream) {
    (void)in_sizes; (void)n_in; (void)out_size;
    const float* x    = (const float*)d_in[0];
    const float* Sw_w = (const float*)d_in[1];
    const float* Sw_b = (const float*)d_in[2];
    const float* Uz_w = (const float*)d_in[3];
    const float* Uz_b = (const float*)d_in[4];
    const float* Wz_w = (const float*)d_in[5];
    const float* Wz_b = (const float*)d_in[6];
    const float* Ug_w = (const float*)d_in[7];
    const float* Ug_b = (const float*)d_in[8];
    const float* Wg_w = (const float*)d_in[9];
    const float* Wg_b = (const float*)d_in[10];
    const float* Ur_w = (const float*)d_in[11];
    const float* Ur_b = (const float*)d_in[12];
    const float* Uh_w = (const float*)d_in[13];
    const float* Uh_b = (const float*)d_in[14];
    const float* ow   = (const float*)d_in[15];
    const float* ob   = (const float*)d_in[16];
    char* ws = (char*)d_ws;

    prep_big<<<4096, 64, 0, stream>>>(Wz_w, Wg_w, ws);
    prep_x<<<384, 64, 0, stream>>>(Uz_w, Ur_w, Uh_w, Ug_w, Sw_w, ws + WS_XT);
    prep_bias<<<4, 256, 0, stream>>>(Uz_b, Wz_b, Ur_b, Uh_b, Ug_b, Wg_b, Sw_b,
                                     (float*)(ws + WS_BIAS));

    // Streams: S (2 KiB/row) + G packed (2 KiB/row) = 4 KiB/row, from 4.5 MiB.
    size_t chunk_rows = 0;
    if (ws_size > WS_S2) {
        size_t avail = ws_size - WS_S2;
        chunk_rows = (avail / 4096) & ~(size_t)63;
        if (chunk_rows > 65536) chunk_rows = 65536;
    }

    if (chunk_rows >= 4096) {
        const int LA = 131072 + 4096;          // k_head
        const int LB = 131072 + 4096 + 4096;   // k_lyr
        hipFuncSetAttribute(reinterpret_cast<const void*>(k_head),
                            hipFuncAttributeMaxDynamicSharedMemorySize, LA);
        hipFuncSetAttribute(reinterpret_cast<const void*>(k_lyr),
                            hipFuncAttributeMaxDynamicSharedMemorySize, LB);
        char* Sg = ws + WS_S2;
        char* Gp = Sg + chunk_rows * 2048;
        for (size_t done = 0; done < 65536; done += chunk_rows) {
            size_t rows = 65536 - done;
            if (rows > chunk_rows) rows = chunk_rows;
            int grid = (int)(rows / 64);
            const float* xc = x + done * 16;
            float* oc = (float*)d_out + done;
            k_head<<<grid, 1024, LA, stream>>>(xc, ws, Sg, Gp);
            for (int L = 0; L < 4; ++L)
                k_lyr<<<grid, 1024, LB, stream>>>(xc, ws, Sg, Gp, (L == 3) ? 1 : 0,
                                                  ow, ob, oc);
        }
    } else {
        const int ldsBytes = 131072 + 3072 + 1024;
        hipFuncSetAttribute(reinterpret_cast<const void*>(dgm_main),
                            hipFuncAttributeMaxDynamicSharedMemorySize, ldsBytes);
        dgm_main<<<65536 / 32, 512, ldsBytes, stream>>>(x, ow, ob, ws, (float*)d_out);
    }
}

// Round 6
// 3538.881 us; speedup vs baseline: 1.6047x; 1.6047x over previous
//
#include <hip/hip_runtime.h>
#include <hip/hip_bf16.h>

// DGMNet: B=65536, IN=16, H=1024, L=4, OUT=1. All I/O fp32, bf16 MFMA inside.
// Round-6: persistent mega-kernel. grid=256 WGs x 1024 thr (1 WG/CU, 16 waves,
// 4 waves/SIMD). Each WG owns 4 row-tiles of 64 rows and runs the WHOLE
// 4-layer recurrence with S (and SR) resident in LDS -> S stream eliminated.
// G and Z*S go to per-WG 128KB slots (nt, same-thread packed). One weight
// table per GEMM pass (Wz or Wg), tables are the only L2-allocating traffic.
// No layer-long packed registers (round-5 spill lesson) -> no spills.

typedef float f32x4 __attribute__((ext_vector_type(4)));
typedef __bf16 bf16x8 __attribute__((ext_vector_type(8)));
typedef unsigned int u32x4 __attribute__((ext_vector_type(4)));

#define MFMA16 __builtin_amdgcn_mfma_f32_16x16x32_bf16

// ---------- ws layout ----------
#define WS_WZ   0u
#define WS_WG   (2u << 20)
#define WS_XT   (4u << 20)
#define WS_BIAS ((4u << 20) + 6u * 65536u)
#define WS_GB   ((size_t)8 << 20)                    // G slots: 256 x 128KB = 32MB
#define WS_ZB   (WS_GB + ((size_t)32 << 20))         // ZS slots: 32MB
#define WS_NEED2 (WS_ZB + ((size_t)32 << 20))        // 72MB total

static __device__ __forceinline__ unsigned short f2bf(float f) {
    __hip_bfloat16 h = __float2bfloat16(f);
    union { __hip_bfloat16 h; unsigned short u; } c; c.h = h; return c.u;
}
static __device__ __forceinline__ float bf2f(unsigned short u) {
    union { unsigned int u; float f; } c; c.u = ((unsigned int)u) << 16; return c.f;
}
static __device__ __forceinline__ float fast_tanh(float x) {
    float e = __expf(2.0f * x);
    return 1.0f - 2.0f * __builtin_amdgcn_rcpf(e + 1.0f);
}
// LDS swizzle for [64][1024] bf16 tile (G4 bank-conflict fix)
static __device__ __forceinline__ unsigned int swoff(int row, int kelem) {
    unsigned int a = (unsigned int)(row * 2048 + kelem * 2);
    return a ^ (unsigned int)((row & 7) << 4);
}
static __device__ __forceinline__ u32x4 ntl4(const void* p) {
    return __builtin_nontemporal_load((const u32x4*)p);
}
static __device__ __forceinline__ void nts4(void* p, u32x4 v) {
    __builtin_nontemporal_store(v, (u32x4*)p);
}

// ---------------- prep kernels ----------------
__global__ void prep_big(const float* __restrict__ Wz, const float* __restrict__ Wg,
                         char* __restrict__ ws) {
    int bid = blockIdx.x;                 // 4096 blocks: mat(2) x ks(32) x cf(64)
    int mat = bid >> 11, rem = bid & 2047;
    int ks = rem >> 6, cf = rem & 63;
    const float* src = mat ? Wg : Wz;
    char* dst = ws + ((size_t)mat << 21) + ((size_t)(ks * 64 + cf) << 10);
    int l = threadIdx.x;
    int col = cf * 16 + (l & 15);
    int kb  = ks * 32 + ((l >> 4) << 3);
    unsigned short* d = (unsigned short*)(dst + l * 16);
    #pragma unroll
    for (int j = 0; j < 8; ++j) d[j] = f2bf(src[col * 1024 + kb + j]);
}

__global__ void prep_x(const float* __restrict__ Uz, const float* __restrict__ Ur,
                       const float* __restrict__ Uh, const float* __restrict__ Ug,
                       const float* __restrict__ Sw, char* __restrict__ xt) {
    int bid = blockIdx.x;                 // 384 blocks: gate(6) x cf(64)
    int g_ = bid >> 6, cf = bid & 63;
    int l = threadIdx.x;
    int col = cf * 16 + (l & 15);
    int kb  = (l >> 4) << 3;
    unsigned short* d = (unsigned short*)(xt + ((size_t)(g_ * 64 + cf) << 10) + l * 16);
    #pragma unroll
    for (int j = 0; j < 8; ++j) {
        int k = kb + j;
        float v = 0.0f;
        if (k < 16) {
            int idx = col * 16 + k;
            switch (g_) {
                case 0: v = Uz[idx]; break;
                case 1: v = Ur[idx]; break;
                case 2: v = Uh[idx]; break;
                case 3: v = Ug[idx]; break;
                case 4: v = Ur[idx] - Ug[idx]; break;
                case 5: v = Sw[idx]; break;
            }
        }
        d[j] = f2bf(v);
    }
}

__global__ void prep_bias(const float* __restrict__ Uz_b, const float* __restrict__ Wz_b,
                          const float* __restrict__ Ur_b, const float* __restrict__ Uh_b,
                          const float* __restrict__ Ug_b, const float* __restrict__ Wg_b,
                          const float* __restrict__ Sw_b, float* __restrict__ dst) {
    int i = blockIdx.x * 256 + threadIdx.x;
    dst[i]        = Uz_b[i] + Wz_b[i];        // bz
    dst[1024 + i] = Ur_b[i] + Wg_b[i];        // br
    dst[2048 + i] = Uh_b[i] + Wg_b[i];        // bh
    dst[3072 + i] = Ug_b[i] + Wg_b[i];        // bg
    dst[4096 + i] = Sw_b[i];                  // bs
}

// ---------------- shared device helpers (16-wave, M=64, full width) ----------------
static __device__ __forceinline__ void stage_xb(const float* __restrict__ x,
                                                unsigned short* xb, int t, int tid) {
    for (int i = tid; i < 64 * 32; i += 1024) {
        int r = i >> 5, c = i & 31;
        float v = (c < 16) ? x[(size_t)(t * 64 + r) * 16 + c] : 0.0f;
        xb[i] = f2bf(v);
    }
}

static __device__ __forceinline__ void mmx16(f32x4 (&acc)[4][4], const char* __restrict__ xtab,
                                             const unsigned short* xb, int lane, int wv) {
    const int c15 = lane & 15, h = lane >> 4;
    bf16x8 a[4];
    #pragma unroll
    for (int rf = 0; rf < 4; ++rf)
        a[rf] = *(const bf16x8*)(xb + (c15 + 16 * rf) * 32 + h * 8);
    #pragma unroll
    for (int cf = 0; cf < 4; ++cf) {
        bf16x8 b = *(const bf16x8*)(xtab + ((wv * 4 + cf) << 10) + lane * 16);
        #pragma unroll
        for (int rf = 0; rf < 4; ++rf) acc[rf][cf] = MFMA16(a[rf], b, acc[rf][cf], 0, 0, 0);
    }
}

static __device__ __forceinline__ void mms16(f32x4 (&acc)[4][4], const char* __restrict__ stab,
                                             const char* sb, int lane, int wv) {
    const int c15 = lane & 15, h = lane >> 4;
    #pragma unroll 2
    for (int ks = 0; ks < 32; ++ks) {
        const char* bp = stab + ((size_t)(ks * 64 + wv * 4) << 10) + lane * 16;
        bf16x8 b[4];
        #pragma unroll
        for (int cf = 0; cf < 4; ++cf) b[cf] = *(const bf16x8*)(bp + (cf << 10));
        bf16x8 a[4];
        #pragma unroll
        for (int rf = 0; rf < 4; ++rf)
            a[rf] = *(const bf16x8*)(sb + swoff(c15 + 16 * rf, (ks << 5) + (h << 3)));
        #pragma unroll
        for (int cf = 0; cf < 4; ++cf)
            #pragma unroll
            for (int rf = 0; rf < 4; ++rf)
                acc[rf][cf] = MFMA16(a[rf], b[cf], acc[rf][cf], 0, 0, 0);
    }
}

#define ZERO_ACC(acc) { _Pragma("unroll") for (int rf_ = 0; rf_ < 4; ++rf_) \
    _Pragma("unroll") for (int cf_ = 0; cf_ < 4; ++cf_) acc[rf_][cf_] = (f32x4)0.0f; }

// ---------------- the persistent mega-kernel ----------------
__global__ __launch_bounds__(1024, 4)
void mega(const float* __restrict__ x, const char* __restrict__ ws,
          const float* __restrict__ ow, const float* __restrict__ ob,
          float* __restrict__ outp, char* __restrict__ Gb, char* __restrict__ Zb) {
    extern __shared__ char lds[];
    char* sbuf = lds;                                   // 128 KiB: S / SR / newS
    unsigned short* xb = (unsigned short*)(lds + 131072); // 4 KiB
    float* red = (float*)(lds + 131072 + 4096);         // 4 KiB
    const int tid = threadIdx.x, lane = tid & 63, wv = tid >> 6;
    const int c15 = lane & 15, h = lane >> 4;
    const int wg = blockIdx.x;
    char* gslot = Gb + ((size_t)wg << 17);              // 128 KiB per WG
    char* zslot = Zb + ((size_t)wg << 17);

    const float* BZ = (const float*)(ws + WS_BIAS);
    const float* BR = BZ + 1024;
    const float* BH = BZ + 2048;
    const float* BG = BZ + 3072;
    const float* BS = BZ + 4096;

    #pragma clang loop unroll(disable)
    for (int rt = 0; rt < 4; ++rt) {
        const int t = rt * 256 + wg;                    // row-tile: rows t*64..t*64+63
        stage_xb(x, xb, t, tid);
        __syncthreads();

        f32x4 acc[4][4];
        // ---- S1 = x @ Sw^T + bs (raw) -> sbuf ----
        ZERO_ACC(acc);
        mmx16(acc, ws + WS_XT + 5 * 65536, xb, lane, wv);
        #pragma unroll
        for (int cf = 0; cf < 4; ++cf) {
            int col = (wv << 6) + (cf << 4) + c15;
            float b = BS[col];
            #pragma unroll
            for (int rf = 0; rf < 4; ++rf)
                #pragma unroll
                for (int r = 0; r < 4; ++r) {
                    int row = (rf << 4) + (h << 2) + r;
                    *(unsigned short*)(sbuf + swoff(row, col)) = f2bf(acc[rf][cf][r] + b);
                }
        }
        __syncthreads();

        // ---- G = tanh(ux_g + S1@Wg^T + bg) -> gslot (nt, per-thread packed) ----
        ZERO_ACC(acc);
        mmx16(acc, ws + WS_XT + 3 * 65536, xb, lane, wv);
        mms16(acc, ws + WS_WG, sbuf, lane, wv);
        {
            unsigned int pk[32];
            #pragma unroll
            for (int cf = 0; cf < 4; ++cf) {
                int col = (wv << 6) + (cf << 4) + c15;
                float b = BG[col];
                #pragma unroll
                for (int rf = 0; rf < 4; ++rf) {
                    float v[4];
                    #pragma unroll
                    for (int r = 0; r < 4; ++r) v[r] = fast_tanh(acc[rf][cf][r] + b);
                    pk[(rf * 4 + cf) * 2 + 0] = (unsigned int)f2bf(v[0]) | ((unsigned int)f2bf(v[1]) << 16);
                    pk[(rf * 4 + cf) * 2 + 1] = (unsigned int)f2bf(v[2]) | ((unsigned int)f2bf(v[3]) << 16);
                }
            }
            #pragma unroll
            for (int w = 0; w < 8; ++w) {
                u32x4 q = { pk[w * 4], pk[w * 4 + 1], pk[w * 4 + 2], pk[w * 4 + 3] };
                nts4(gslot + w * 16384 + tid * 16, q);
            }
        }
        // (no LDS writes since S1 -> no barrier needed before Z's reads)

        // ---- 4-layer recurrence, S resident in sbuf ----
        #pragma clang loop unroll(disable)
        for (int L = 0; L < 4; ++L) {
            // Z pass (Wz): ZS -> zslot (nt), freeing registers for R/H
            ZERO_ACC(acc);
            mmx16(acc, ws + WS_XT + 0 * 65536, xb, lane, wv);
            mms16(acc, ws + WS_WZ, sbuf, lane, wv);
            {
                unsigned int pk[32];
                #pragma unroll
                for (int cf = 0; cf < 4; ++cf) {
                    int col = (wv << 6) + (cf << 4) + c15;
                    float bzl = BZ[col];
                    #pragma unroll
                    for (int rf = 0; rf < 4; ++rf) {
                        float v[4];
                        #pragma unroll
                        for (int r = 0; r < 4; ++r) {
                            int row = (rf << 4) + (h << 2) + r;
                            float z = fast_tanh(acc[rf][cf][r] + bzl);
                            v[r] = z * bf2f(*(const unsigned short*)(sbuf + swoff(row, col)));
                        }
                        pk[(rf * 4 + cf) * 2 + 0] = (unsigned int)f2bf(v[0]) | ((unsigned int)f2bf(v[1]) << 16);
                        pk[(rf * 4 + cf) * 2 + 1] = (unsigned int)f2bf(v[2]) | ((unsigned int)f2bf(v[3]) << 16);
                    }
                }
                #pragma unroll
                for (int w = 0; w < 8; ++w) {
                    u32x4 q = { pk[w * 4], pk[w * 4 + 1], pk[w * 4 + 2], pk[w * 4 + 3] };
                    nts4(zslot + w * 16384 + tid * 16, q);
                }
            }

            // R pass (Wg): srp (transient) -> SR into sbuf in place
            ZERO_ACC(acc);
            mmx16(acc, ws + WS_XT + 1 * 65536, xb, lane, wv);
            mms16(acc, ws + WS_WG, sbuf, lane, wv);
            {
                unsigned int srp[32];
                #pragma unroll
                for (int cf = 0; cf < 4; ++cf) {
                    int col = (wv << 6) + (cf << 4) + c15;
                    float brl = BR[col];
                    #pragma unroll
                    for (int rf = 0; rf < 4; ++rf) {
                        float v[4];
                        #pragma unroll
                        for (int r = 0; r < 4; ++r) {
                            int row = (rf << 4) + (h << 2) + r;
                            float rv = fast_tanh(acc[rf][cf][r] + brl);
                            v[r] = rv * bf2f(*(const unsigned short*)(sbuf + swoff(row, col)));
                        }
                        srp[(rf * 4 + cf) * 2 + 0] = (unsigned int)f2bf(v[0]) | ((unsigned int)f2bf(v[1]) << 16);
                        srp[(rf * 4 + cf) * 2 + 1] = (unsigned int)f2bf(v[2]) | ((unsigned int)f2bf(v[3]) << 16);
                    }
                }
                __syncthreads();   // all S reads (Z + R passes) complete
                #pragma unroll
                for (int cf = 0; cf < 4; ++cf) {
                    int col = (wv << 6) + (cf << 4) + c15;
                    #pragma unroll
                    for (int rf = 0; rf < 4; ++rf)
                        #pragma unroll
                        for (int r = 0; r < 4; ++r) {
                            int row = (rf << 4) + (h << 2) + r;
                            unsigned short u = (unsigned short)((srp[(rf * 4 + cf) * 2 + (r >> 1)] >> ((r & 1) * 16)) & 0xffff);
                            *(unsigned short*)(sbuf + swoff(row, col)) = u;
                        }
                }
            }
            __syncthreads();   // SR ready

            // H pass (Wg)
            ZERO_ACC(acc);
            mmx16(acc, ws + WS_XT + 2 * 65536, xb, lane, wv);
            mms16(acc, ws + WS_WG, sbuf, lane, wv);
            __syncthreads();   // all SR reads done before newS writes

            if (L < 3) {
                #pragma unroll
                for (int w = 0; w < 8; ++w) {
                    u32x4 g4 = ntl4(gslot + w * 16384 + tid * 16);
                    u32x4 z4 = ntl4(zslot + w * 16384 + tid * 16);
                    #pragma unroll
                    for (int jj = 0; jj < 2; ++jj) {
                        int rfcf = w * 2 + jj;
                        int rf = rfcf >> 2, cf = rfcf & 3;
                        int col = (wv << 6) + (cf << 4) + c15;
                        float bhl = BH[col];
                        #pragma unroll
                        for (int r = 0; r < 4; ++r) {
                            int row = (rf << 4) + (h << 2) + r;
                            float g  = bf2f((unsigned short)((g4[jj * 2 + (r >> 1)] >> ((r & 1) * 16)) & 0xffff));
                            float zs = bf2f((unsigned short)((z4[jj * 2 + (r >> 1)] >> ((r & 1) * 16)) & 0xffff));
                            float hv = fast_tanh(acc[rf][cf][r] + bhl);
                            float o  = (1.0f - g) * hv + zs;
                            *(unsigned short*)(sbuf + swoff(row, col)) = f2bf(fast_tanh(o));
                        }
                    }
                }
                __syncthreads();   // newS visible for next layer
            } else {
                float po[16];
                #pragma unroll
                for (int i = 0; i < 16; ++i) po[i] = 0.0f;
                #pragma unroll
                for (int w = 0; w < 8; ++w) {
                    u32x4 g4 = ntl4(gslot + w * 16384 + tid * 16);
                    u32x4 z4 = ntl4(zslot + w * 16384 + tid * 16);
                    #pragma unroll
                    for (int jj = 0; jj < 2; ++jj) {
                        int rfcf = w * 2 + jj;
                        int rf = rfcf >> 2, cf = rfcf & 3;
                        int col = (wv << 6) + (cf << 4) + c15;
                        float bhl = BH[col];
                        float oww = ow[col];
                        #pragma unroll
                        for (int r = 0; r < 4; ++r) {
                            float g  = bf2f((unsigned short)((g4[jj * 2 + (r >> 1)] >> ((r & 1) * 16)) & 0xffff));
                            float zs = bf2f((unsigned short)((z4[jj * 2 + (r >> 1)] >> ((r & 1) * 16)) & 0xffff));
                            float hv = fast_tanh(acc[rf][cf][r] + bhl);
                            po[(rf << 2) + r] += ((1.0f - g) * hv + zs) * oww;
                        }
                    }
                }
                #pragma unroll
                for (int off = 1; off < 16; off <<= 1)
                    #pragma unroll
                    for (int i = 0; i < 16; ++i) po[i] += __shfl_xor(po[i], off);
                if (c15 == 0) {
                    #pragma unroll
                    for (int rf = 0; rf < 4; ++rf)
                        #pragma unroll
                        for (int r = 0; r < 4; ++r)
                            red[wv * 64 + (rf << 4) + (h << 2) + r] = po[(rf << 2) + r];
                }
                __syncthreads();
                if (tid < 64) {
                    float s = ob[0];
                    #pragma unroll
                    for (int w = 0; w < 16; ++w) s += red[w * 64 + tid];
                    outp[t * 64 + tid] = s;
                }
                __syncthreads();   // red/sbuf free for next row-tile
            }
        }
    }
}

// ================= FALLBACK PATH: round-1 fused kernel (proven) =================

static __device__ __forceinline__ void mm_x(f32x4 acc[2][8], const char* __restrict__ xtab,
                                            const unsigned short* __restrict__ xb,
                                            int lane, int wv) {
    const int c15 = lane & 15, h = lane >> 4;
    bf16x8 a0 = *(const bf16x8*)(xb + c15 * 48 + h * 8);
    bf16x8 a1 = *(const bf16x8*)(xb + (c15 + 16) * 48 + h * 8);
    #pragma unroll
    for (int cf = 0; cf < 8; ++cf) {
        bf16x8 b = *(const bf16x8*)(xtab + ((wv * 8 + cf) << 10) + lane * 16);
        acc[0][cf] = MFMA16(a0, b, acc[0][cf], 0, 0, 0);
        acc[1][cf] = MFMA16(a1, b, acc[1][cf], 0, 0, 0);
    }
}

static __device__ __forceinline__ void mm_s(f32x4 acc[2][8], const char* __restrict__ stab,
                                            const char* __restrict__ sb, int lane, int wv) {
    const int c15 = lane & 15, h = lane >> 4;
    #pragma unroll 2
    for (int ks = 0; ks < 32; ++ks) {
        const char* bp = stab + ((size_t)(ks * 64 + wv * 8) << 10) + lane * 16;
        bf16x8 b[8];
        #pragma unroll
        for (int cf = 0; cf < 8; ++cf) b[cf] = *(const bf16x8*)(bp + (cf << 10));
        bf16x8 a0 = *(const bf16x8*)(sb + swoff(c15,      (ks << 5) + (h << 3)));
        bf16x8 a1 = *(const bf16x8*)(sb + swoff(c15 + 16, (ks << 5) + (h << 3)));
        #pragma unroll
        for (int cf = 0; cf < 8; ++cf) {
            acc[0][cf] = MFMA16(a0, b[cf], acc[0][cf], 0, 0, 0);
            acc[1][cf] = MFMA16(a1, b[cf], acc[1][cf], 0, 0, 0);
        }
    }
}

__global__ __launch_bounds__(512, 2)
void dgm_main(const float* __restrict__ x, const float* __restrict__ out_w,
              const float* __restrict__ out_b, const char* __restrict__ ws,
              float* __restrict__ out) {
    extern __shared__ char lds[];
    char* sbuf0 = lds;
    char* sbuf1 = lds + 65536;
    unsigned short* xb = (unsigned short*)(lds + 131072);
    float* red = (float*)(lds + 131072 + 3072);

    const int tid = threadIdx.x, lane = tid & 63, wv = tid >> 6;
    const int c15 = lane & 15, h = lane >> 4;
    const int t = blockIdx.x;

    const char* WZ = ws + WS_WZ;
    const char* WG = ws + WS_WG;
    const char* XT = ws + WS_XT;
    const float* BZ = (const float*)(ws + WS_BIAS);
    const float* BR = BZ + 1024;
    const float* BH = BZ + 2048;
    const float* BG = BZ + 3072;
    const float* BS = BZ + 4096;

    for (int i = tid; i < 32 * 48; i += 512) {
        int r_ = i / 48, c_ = i % 48;
        float v = (c_ < 16) ? x[(t * 32 + r_) * 16 + c_] : 0.0f;
        xb[r_ * 48 + c_] = f2bf(v);
    }
    __syncthreads();

    f32x4 acc[2][8];
    unsigned int g1m[2][8][2];
    unsigned int zs[2][8][2];
    float po[8];
    #pragma unroll
    for (int i = 0; i < 8; ++i) po[i] = 0.0f;

    #pragma unroll
    for (int rf = 0; rf < 2; ++rf)
        #pragma unroll
        for (int cf = 0; cf < 8; ++cf) acc[rf][cf] = (f32x4)0.0f;
    mm_x(acc, XT + 5 * 65536, xb, lane, wv);
    #pragma unroll
    for (int cf = 0; cf < 8; ++cf) {
        int col = (wv << 7) + (cf << 4) + c15;
        float b = BS[col];
        #pragma unroll
        for (int rf = 0; rf < 2; ++rf)
            #pragma unroll
            for (int r = 0; r < 4; ++r) {
                int row = (rf << 4) + (h << 2) + r;
                *(unsigned short*)(sbuf0 + swoff(row, col)) = f2bf(acc[rf][cf][r] + b);
            }
    }
    __syncthreads();

    {
        #pragma unroll
        for (int rf = 0; rf < 2; ++rf)
            #pragma unroll
            for (int cf = 0; cf < 8; ++cf) acc[rf][cf] = (f32x4)0.0f;
        mm_x(acc, XT + 3 * 65536, xb, lane, wv);
        mm_s(acc, WG, sbuf0, lane, wv);
        unsigned int wgx[2][8][2];
        #pragma unroll
        for (int rf = 0; rf < 2; ++rf)
            #pragma unroll
            for (int cf = 0; cf < 8; ++cf) {
                wgx[rf][cf][0] = (unsigned int)f2bf(acc[rf][cf][0]) |
                                 ((unsigned int)f2bf(acc[rf][cf][1]) << 16);
                wgx[rf][cf][1] = (unsigned int)f2bf(acc[rf][cf][2]) |
                                 ((unsigned int)f2bf(acc[rf][cf][3]) << 16);
            }
        #pragma unroll
        for (int rf = 0; rf < 2; ++rf)
            #pragma unroll
            for (int cf = 0; cf < 8; ++cf) acc[rf][cf] = (f32x4)0.0f;
        mm_x(acc, XT + 4 * 65536, xb, lane, wv);
        #pragma unroll
        for (int cf = 0; cf < 8; ++cf) {
            int col = (wv << 7) + (cf << 4) + c15;
            float brl = BR[col], bgl = BG[col];
            #pragma unroll
            for (int rf = 0; rf < 2; ++rf) {
                float g1v[4];
                #pragma unroll
                for (int r = 0; r < 4; ++r) {
                    int row = (rf << 4) + (h << 2) + r;
                    float wgv = bf2f((unsigned short)((wgx[rf][cf][r >> 1] >> ((r & 1) * 16)) & 0xffff));
                    float rv = fast_tanh(wgv + acc[rf][cf][r] + brl);
                    float s1 = bf2f(*(const unsigned short*)(sbuf0 + swoff(row, col)));
                    *(unsigned short*)(sbuf1 + swoff(row, col)) = f2bf(s1 * rv);
                    g1v[r] = 1.0f - fast_tanh(wgv + bgl);
                }
                g1m[rf][cf][0] = (unsigned int)f2bf(g1v[0]) | ((unsigned int)f2bf(g1v[1]) << 16);
                g1m[rf][cf][1] = (unsigned int)f2bf(g1v[2]) | ((unsigned int)f2bf(g1v[3]) << 16);
            }
        }
    }
    __syncthreads();

    char* cur = sbuf0;
    char* oth = sbuf1;
    #pragma clang loop unroll(disable)
    for (int L = 0; L < 4; ++L) {
        #pragma unroll
        for (int rf = 0; rf < 2; ++rf)
            #pragma unroll
            for (int cf = 0; cf < 8; ++cf) acc[rf][cf] = (f32x4)0.0f;
        mm_x(acc, XT + 0 * 65536, xb, lane, wv);
        mm_s(acc, WZ, cur, lane, wv);
        #pragma unroll
        for (int cf = 0; cf < 8; ++cf) {
            int col = (wv << 7) + (cf << 4) + c15;
            float bzl = BZ[col];
            #pragma unroll
            for (int rf = 0; rf < 2; ++rf) {
                float zv[4];
                #pragma unroll
                for (int r = 0; r < 4; ++r) {
                    int row = (rf << 4) + (h << 2) + r;
                    float z = fast_tanh(acc[rf][cf][r] + bzl);
                    float s = bf2f(*(const unsigned short*)(cur + swoff(row, col)));
                    zv[r] = z * s;
                }
                zs[rf][cf][0] = (unsigned int)f2bf(zv[0]) | ((unsigned int)f2bf(zv[1]) << 16);
                zs[rf][cf][1] = (unsigned int)f2bf(zv[2]) | ((unsigned int)f2bf(zv[3]) << 16);
            }
        }
        if (L > 0) {
            #pragma unroll
            for (int rf = 0; rf < 2; ++rf)
                #pragma unroll
                for (int cf = 0; cf < 8; ++cf) acc[rf][cf] = (f32x4)0.0f;
            mm_x(acc, XT + 1 * 65536, xb, lane, wv);
            mm_s(acc, WG, cur, lane, wv);
            #pragma unroll
            for (int cf = 0; cf < 8; ++cf) {
                int col = (wv << 7) + (cf << 4) + c15;
                float brl = BR[col];
                #pragma unroll
                for (int rf = 0; rf < 2; ++rf)
                    #pragma unroll
                    for (int r = 0; r < 4; ++r) {
                        int row = (rf << 4) + (h << 2) + r;
                        float rv = fast_tanh(acc[rf][cf][r] + brl);
                        float s = bf2f(*(const unsigned short*)(cur + swoff(row, col)));
                        *(unsigned short*)(oth + swoff(row, col)) = f2bf(s * rv);
                    }
            }
        }
        __syncthreads();
        #pragma unroll
        for (int rf = 0; rf < 2; ++rf)
            #pragma unroll
            for (int cf = 0; cf < 8; ++cf) acc[rf][cf] = (f32x4)0.0f;
        mm_x(acc, XT + 2 * 65536, xb, lane, wv);
        mm_s(acc, WG, oth, lane, wv);
        __syncthreads();
        if (L < 3) {
            #pragma unroll
            for (int cf = 0; cf < 8; ++cf) {
                int col = (wv << 7) + (cf << 4) + c15;
                float bhl = BH[col];
                #pragma unroll
                for (int rf = 0; rf < 2; ++rf)
                    #pragma unroll
                    for (int r = 0; r < 4; ++r) {
                        int row = (rf << 4) + (h << 2) + r;
                        float hv = fast_tanh(acc[rf][cf][r] + bhl);
                        float g1 = bf2f((unsigned short)((g1m[rf][cf][r >> 1] >> ((r & 1) * 16)) & 0xffff));
                        float zsv = bf2f((unsigned short)((zs[rf][cf][r >> 1] >> ((r & 1) * 16)) & 0xffff));
                        float o = g1 * hv + zsv;
                        *(unsigned short*)(oth + swoff(row, col)) = f2bf(fast_tanh(o));
                    }
            }
        } else {
            #pragma unroll
            for (int cf = 0; cf < 8; ++cf) {
                int col = (wv << 7) + (cf << 4) + c15;
                float bhl = BH[col];
                float oww = out_w[col];
                #pragma unroll
                for (int rf = 0; rf < 2; ++rf)
                    #pragma unroll
                    for (int r = 0; r < 4; ++r) {
                        float hv = fast_tanh(acc[rf][cf][r] + bhl);
                        float g1 = bf2f((unsigned short)((g1m[rf][cf][r >> 1] >> ((r & 1) * 16)) & 0xffff));
                        float zsv = bf2f((unsigned short)((zs[rf][cf][r >> 1] >> ((r & 1) * 16)) & 0xffff));
                        po[(rf << 2) + r] += (g1 * hv + zsv) * oww;
                    }
            }
        }
        __syncthreads();
        char* tmp = cur; cur = oth; oth = tmp;
    }

    #pragma unroll
    for (int off = 1; off < 16; off <<= 1)
        #pragma unroll
        for (int i = 0; i < 8; ++i) po[i] += __shfl_xor(po[i], off);
    if (c15 == 0) {
        #pragma unroll
        for (int rf = 0; rf < 2; ++rf)
            #pragma unroll
            for (int r = 0; r < 4; ++r)
                red[wv * 32 + (rf << 4) + (h << 2) + r] = po[(rf << 2) + r];
    }
    __syncthreads();
    if (tid < 32) {
        float s = out_b[0];
        #pragma unroll
        for (int w = 0; w < 8; ++w) s += red[w * 32 + tid];
        out[t * 32 + tid] = s;
    }
}

// ---------------- host ----------------
extern "C" void kernel_launch(void* const* d_in, const int* in_sizes, int n_in,
                              void* d_out, int out_size, void* d_ws, size_t ws_size,
                              hipStream_t stream) {
    (void)in_sizes; (void)n_in; (void)out_size;
    const float* x    = (const float*)d_in[0];
    const float* Sw_w = (const float*)d_in[1];
    const float* Sw_b = (const float*)d_in[2];
    const float* Uz_w = (const float*)d_in[3];
    const float* Uz_b = (const float*)d_in[4];
    const float* Wz_w = (const float*)d_in[5];
    const float* Wz_b = (const float*)d_in[6];
    const float* Ug_w = (const float*)d_in[7];
    const float* Ug_b = (const float*)d_in[8];
    const float* Wg_w = (const float*)d_in[9];
    const float* Wg_b = (const float*)d_in[10];
    const float* Ur_w = (const float*)d_in[11];
    const float* Ur_b = (const float*)d_in[12];
    const float* Uh_w = (const float*)d_in[13];
    const float* Uh_b = (const float*)d_in[14];
    const float* ow   = (const float*)d_in[15];
    const float* ob   = (const float*)d_in[16];
    char* ws = (char*)d_ws;

    prep_big<<<4096, 64, 0, stream>>>(Wz_w, Wg_w, ws);
    prep_x<<<384, 64, 0, stream>>>(Uz_w, Ur_w, Uh_w, Ug_w, Sw_w, ws + WS_XT);
    prep_bias<<<4, 256, 0, stream>>>(Uz_b, Wz_b, Ur_b, Uh_b, Ug_b, Wg_b, Sw_b,
                                     (float*)(ws + WS_BIAS));

    if (ws_size >= WS_NEED2) {
        const int LM = 131072 + 4096 + 4096;   // 136 KiB
        hipFuncSetAttribute(reinterpret_cast<const void*>(mega),
                            hipFuncAttributeMaxDynamicSharedMemorySize, LM);
        mega<<<256, 1024, LM, stream>>>(x, ws, ow, ob, (float*)d_out,
                                        ws + WS_GB, ws + WS_ZB);
    } else {
        const int ldsBytes = 131072 + 3072 + 1024;
        hipFuncSetAttribute(reinterpret_cast<const void*>(dgm_main),
                            hipFuncAttributeMaxDynamicSharedMemorySize, ldsBytes);
        dgm_main<<<65536 / 32, 512, ldsBytes, stream>>>(x, ow, ob, ws, (float*)d_out);
    }
}